// Round 23
// baseline (286.784 us; speedup 1.0000x reference)
//
#include <hip/hip_runtime.h>
#include <cstdint>
#include <cstddef>

typedef unsigned short u16;
typedef unsigned int   u32;
typedef __attribute__((ext_vector_type(8))) short v8s;   // 8 bf16 (4 VGPRs) MFMA A/B frag
typedef __attribute__((ext_vector_type(4))) float v4f;   // 4 fp32 MFMA C/D frag

// Fixed problem shape
#define B_   2
#define N_   2048
#define C_   1024
#define H_   16
#define D_   64
#define HID_ 4096
#define M_   4096   // B_*N_

static __device__ __forceinline__ float b2f(u32 u) {
    union { u32 i; float f; } x; x.i = u << 16; return x.f;
}
static __device__ __forceinline__ u16 f2b(float f) {
    union { float f; u32 i; } x; x.f = f;
    u32 r = (x.i + 0x7fffu + ((x.i >> 16) & 1u)) >> 16;
    return (u16)r;
}
static __device__ __forceinline__ u32 scale2(u32 raw, float s) {
    float lo = b2f(raw & 0xffffu) * s, hi = b2f(raw >> 16) * s;
    return (u32)f2b(lo) | ((u32)f2b(hi) << 16);
}

// async global->LDS, 16B per lane; LDS dest is wave-uniform base + lane*16
static __device__ __forceinline__ void gload_lds16(const u16* g, u16* l) {
    __builtin_amdgcn_global_load_lds(
        (const __attribute__((address_space(1))) void*)g,
        (__attribute__((address_space(3))) void*)l,
        16, 0, 0);
}

// T1 XCD-aware block swizzle: physical linear id -> logical (x,y); nwg must be %8==0
static __device__ __forceinline__ int2 xcd_swz(int gx, int gy) {
    const int nwg = gx * gy;
    int id = blockIdx.y * gx + blockIdx.x;
    id = (id & 7) * (nwg >> 3) + (id >> 3);
    return make_int2(id % gx, id / gx);
}

// ---------------- fused prologue: weight transpose/cvt + RoPE table + LN1, one launch ------
// ids 0..12287: 32x32 transpose tiles; 12288..12543: cos/sin table; 12544..16639: LN1 rows.
__global__ __launch_bounds__(256) void transpose_all(const float* __restrict__ Wqkv,
                                                     const float* __restrict__ Wproj,
                                                     const float* __restrict__ Wfc1,
                                                     const float* __restrict__ Wfc2,
                                                     u16* __restrict__ Oqkv,
                                                     u16* __restrict__ Oproj,
                                                     u16* __restrict__ Ofc1,
                                                     u16* __restrict__ Ofc2,
                                                     float2* __restrict__ tab,
                                                     const float* __restrict__ xin,
                                                     const float* __restrict__ ln1g,
                                                     const float* __restrict__ ln1b,
                                                     u16* __restrict__ h1out) {
    __shared__ float tile[32][33];
    __shared__ float ps[4], psq[4], stats[2];
    int id = blockIdx.x;
    const int t = threadIdx.x;
    if (id >= 12544) {                 // ---- LN1 row (fp32 x -> bf16 h1) ----
        const int row = id - 12544;
        float4 v = ((const float4*)xin)[(size_t)row * 256 + t];
        float s  = v.x + v.y + v.z + v.w;
        float sq = v.x * v.x + v.y * v.y + v.z * v.z + v.w * v.w;
#pragma unroll
        for (int off = 32; off > 0; off >>= 1) { s += __shfl_down(s, off); sq += __shfl_down(sq, off); }
        if ((t & 63) == 0) { ps[t >> 6] = s; psq[t >> 6] = sq; }
        __syncthreads();
        if (t == 0) {
            float S = ps[0] + ps[1] + ps[2] + ps[3];
            float Q = psq[0] + psq[1] + psq[2] + psq[3];
            float mu  = S * (1.f / 1024.f);
            float var = Q * (1.f / 1024.f) - mu * mu;
            stats[0] = mu; stats[1] = rsqrtf(var + 1e-5f);
        }
        __syncthreads();
        const float mu = stats[0], istd = stats[1];
        float4 gg = ((const float4*)ln1g)[t];
        float4 bb = ((const float4*)ln1b)[t];
        ushort4 o;
        o.x = f2b((v.x - mu) * istd * gg.x + bb.x);
        o.y = f2b((v.y - mu) * istd * gg.y + bb.y);
        o.z = f2b((v.z - mu) * istd * gg.z + bb.z);
        o.w = f2b((v.w - mu) * istd * gg.w + bb.w);
        *(ushort4*)&h1out[(size_t)row * 1024 + t * 4] = o;
        return;
    }
    if (id >= 12288) {                 // ---- RoPE table ----
        const int i = (id - 12288) * 256 + t;
        const int d = i & 31, n = i >> 5;
        float inv = powf(10000.f, -(float)d * (1.f / 32.f));
        float fr = (float)n * inv;
        tab[i] = make_float2(cosf(fr), sinf(fr));
        return;
    }
    const float* in; u16* out; int K, N, nx;
    if (id < 3072)      { in = Wqkv;  out = Oqkv;  K = 1024; N = 3072; nx = 96;  }
    else if (id < 4096) { in = Wproj; out = Oproj; K = 1024; N = 1024; nx = 32;  id -= 3072; }
    else if (id < 8192) { in = Wfc1;  out = Ofc1;  K = 1024; N = 4096; nx = 128; id -= 4096; }
    else                { in = Wfc2;  out = Ofc2;  K = 4096; N = 1024; nx = 32;  id -= 8192; }
    const int n0 = (id % nx) * 32, k0 = (id / nx) * 32;
    const int c = t & 31, r8 = t >> 5;
#pragma unroll
    for (int i = 0; i < 4; ++i)
        tile[r8 + i * 8][c] = in[(size_t)(k0 + r8 + i * 8) * N + n0 + c];
    __syncthreads();
#pragma unroll
    for (int i = 0; i < 4; ++i)
        out[(size_t)(n0 + r8 + i * 8) * K + k0 + c] = f2b(tile[c][r8 + i * 8]);
}

// ---------------- LayerNorm: fp32 in -> bf16 out, one block per row (C=1024) ----------------
__global__ __launch_bounds__(256) void ln_kernel(const float* __restrict__ in,
                                                 const float* __restrict__ g,
                                                 const float* __restrict__ b,
                                                 u16* __restrict__ out) {
    __shared__ float ps[4], psq[4];
    __shared__ float stats[2];
    const int row = blockIdx.x;
    const int t = threadIdx.x;
    float4 v = ((const float4*)in)[(size_t)row * 256 + t];
    float s  = v.x + v.y + v.z + v.w;
    float sq = v.x * v.x + v.y * v.y + v.z * v.z + v.w * v.w;
#pragma unroll
    for (int off = 32; off > 0; off >>= 1) { s += __shfl_down(s, off); sq += __shfl_down(sq, off); }
    if ((t & 63) == 0) { ps[t >> 6] = s; psq[t >> 6] = sq; }
    __syncthreads();
    if (t == 0) {
        float S = ps[0] + ps[1] + ps[2] + ps[3];
        float Q = psq[0] + psq[1] + psq[2] + psq[3];
        float mu  = S * (1.f / 1024.f);
        float var = Q * (1.f / 1024.f) - mu * mu;
        stats[0] = mu; stats[1] = rsqrtf(var + 1e-5f);
    }
    __syncthreads();
    const float mu = stats[0], istd = stats[1];
    float4 gg = ((const float4*)g)[t];
    float4 bb = ((const float4*)b)[t];
    ushort4 o;
    o.x = f2b((v.x - mu) * istd * gg.x + bb.x);
    o.y = f2b((v.y - mu) * istd * gg.y + bb.y);
    o.z = f2b((v.z - mu) * istd * gg.z + bb.z);
    o.w = f2b((v.w - mu) * istd * gg.w + bb.w);
    *(ushort4*)&out[(size_t)row * 1024 + t * 4] = o;
}

// ---------------- GEMM BM=64 x BN=128, BK=64, 3-buffer counted vmcnt (proj, fc2) -----------
__global__ __launch_bounds__(256) void gemm_bk64(const u16* __restrict__ A,
                                                 const u16* __restrict__ Bt,
                                                 const float* __restrict__ bias,
                                                 float* __restrict__ outp,
                                                 const float* __restrict__ resid,
                                                 int Ndim, int Kdim) {
    __shared__ u16 As[3][64 * 64];
    __shared__ u16 Bs[3][128 * 64];
    const int t = threadIdx.x;
    const int lane = t & 63;
    const int w = t >> 6;                 // wave = N-subtile (4 x 32 cols)
    const int2 lb = xcd_swz(gridDim.x, gridDim.y);
    const int m0 = lb.y * 64, n0 = lb.x * 128;
    const int hi = lane >> 4, lo = lane & 15;

    auto STAGE = [&](int buf, int kb) {
#pragma unroll
        for (int j = 0; j < 2; ++j) {     // A: 64 rows x 64 u16 = 512 chunks
            const int c = (w * 2 + j) * 64 + lane;
            const int row = c >> 3, ch = c & 7;
            gload_lds16(&A[(size_t)(m0 + row) * Kdim + kb + ((ch ^ (row & 7)) * 8)],
                        &As[buf][(w * 2 + j) * 512]);
        }
#pragma unroll
        for (int j = 0; j < 4; ++j) {     // B: 128 rows x 64 u16 = 1024 chunks
            const int c = (w * 4 + j) * 64 + lane;
            const int row = c >> 3, ch = c & 7;
            gload_lds16(&Bt[(size_t)(n0 + row) * Kdim + kb + ((ch ^ (row & 7)) * 8)],
                        &Bs[buf][(w * 4 + j) * 512]);
        }
    };

    const v4f vzero = {0.f, 0.f, 0.f, 0.f};
    v4f acc[4][2];
#pragma unroll
    for (int i = 0; i < 4; ++i) { acc[i][0] = vzero; acc[i][1] = vzero; }

    const int nt = Kdim / 64;
    STAGE(0, 0);
    STAGE(1, 64);
    for (int kt = 0; kt < nt; ++kt) {
        if (kt + 1 == nt) asm volatile("s_waitcnt vmcnt(0)" ::: "memory");
        else              asm volatile("s_waitcnt vmcnt(6)" ::: "memory");
        __builtin_amdgcn_s_barrier();
        if (kt + 2 < nt) STAGE((kt + 2) % 3, (kt + 2) * 64);
        const int cur = kt % 3;
#pragma unroll
        for (int ks = 0; ks < 2; ++ks) {
            v8s av[4], bv[2];
#pragma unroll
            for (int m = 0; m < 4; ++m) {
                const int row = m * 16 + lo;
                av[m] = *(const v8s*)&As[cur][row * 64 + (((ks * 4 + hi) ^ (row & 7)) * 8)];
            }
#pragma unroll
            for (int n = 0; n < 2; ++n) {
                const int row = w * 32 + n * 16 + lo;
                bv[n] = *(const v8s*)&Bs[cur][row * 64 + (((ks * 4 + hi) ^ (row & 7)) * 8)];
            }
#pragma unroll
            for (int m = 0; m < 4; ++m)
#pragma unroll
                for (int n = 0; n < 2; ++n)
                    acc[m][n] = __builtin_amdgcn_mfma_f32_16x16x32_bf16(av[m], bv[n], acc[m][n], 0, 0, 0);
        }
    }

#pragma unroll
    for (int m = 0; m < 4; ++m)
#pragma unroll
        for (int n = 0; n < 2; ++n) {
            const int col = n0 + w * 32 + n * 16 + lo;
            const float bsv = bias[col];
#pragma unroll
            for (int r = 0; r < 4; ++r) {
                const int row = m0 + m * 16 + hi * 4 + r;
                outp[(size_t)row * Ndim + col] = acc[m][n][r] + bsv + resid[(size_t)row * Ndim + col];
            }
        }
}

// ---------------- 256x256 8-wave GEMM, 4 phases/K-tile, counted vmcnt -----------------------
// EPI 0: qkv scatter to (3,B,H,N,D) bf16 + fused RoPE (partner = lane^1).  EPI 2: GELU bf16.
__global__ __launch_bounds__(512, 2) void gemm256_epi0(const u16*, const u16*, const float*,
                                                       void*, const float2*, int, int);
template <int EPI>
__global__ __launch_bounds__(512, 2) void gemm256(const u16* __restrict__ A,
                                                  const u16* __restrict__ Bt,
                                                  const float* __restrict__ bias,
                                                  void* __restrict__ outp,
                                                  const float2* __restrict__ tab,
                                                  int Ndim, int Kdim) {
    __shared__ u16 As[2 * 2 * 256 * 32];   // [buf][ks][row][32]
    __shared__ u16 Bs[2 * 2 * 256 * 32];
    const int t = threadIdx.x;             // 0..511
    const int lane = t & 63;
    const int w = t >> 6;                  // 0..7
    const int wr = w >> 2, wc = w & 3;     // 2 x 4 wave grid; per-wave out 128x64
    const int hi = lane >> 4, lo = lane & 15;
    const int2 lb = xcd_swz(gridDim.x, gridDim.y);
    const int m0 = lb.y * 256, n0 = lb.x * 256;
    const int koff = (hi ^ ((lo >> 1) & 3)) * 8;   // swizzled k-chunk for frag reads

    auto STAGEH = [&](u16* lds, const u16* src, int rb, int b, int ks, int kt) {
#pragma unroll
        for (int j = 0; j < 2; ++j) {
            const int c = j * 512 + t;         // 16B chunk id, 0..1023
            const int row = c >> 2;
            const int ch = c & 3;
            gload_lds16(&src[(size_t)(rb + row) * Kdim + kt * 64 + ks * 32 +
                             ((ch ^ ((row >> 1) & 3)) * 8)],
                        &lds[(b * 2 + ks) * 8192 + c * 8]);
        }
    };
    auto RD = [&](const u16* lds, int b, int ks, int row) -> v8s {
        return *(const v8s*)&lds[(b * 2 + ks) * 8192 + row * 32 + koff];
    };

    const v4f vzero = {0.f, 0.f, 0.f, 0.f};
    v4f acc[8][4];
#pragma unroll
    for (int i = 0; i < 8; ++i)
#pragma unroll
        for (int j = 0; j < 4; ++j) acc[i][j] = vzero;

    const int nt = Kdim / 64;
    STAGEH(As, A, m0, 0, 0, 0);
    STAGEH(Bs, Bt, n0, 0, 0, 0);
    STAGEH(As, A, m0, 0, 1, 0);
    STAGEH(Bs, Bt, n0, 0, 1, 0);

    for (int I = 0; I < nt; ++I) {
        const int b = I & 1, nb = b ^ 1;
        const bool pf = (I + 1 < nt);
        v8s av[4], bv[4];
        if (pf) asm volatile("s_waitcnt vmcnt(4)" ::: "memory");
        else    asm volatile("s_waitcnt vmcnt(2)" ::: "memory");
        __builtin_amdgcn_s_barrier();
        // ph1: (mi 0-3, ks0)
#pragma unroll
        for (int n = 0; n < 4; ++n) bv[n] = RD(Bs, b, 0, wc * 64 + n * 16 + lo);
#pragma unroll
        for (int m = 0; m < 4; ++m) av[m] = RD(As, b, 0, wr * 128 + m * 16 + lo);
        if (pf) STAGEH(As, A, m0, nb, 0, I + 1);
        __builtin_amdgcn_s_setprio(1);
#pragma unroll
        for (int m = 0; m < 4; ++m)
#pragma unroll
            for (int n = 0; n < 4; ++n)
                acc[m][n] = __builtin_amdgcn_mfma_f32_16x16x32_bf16(av[m], bv[n], acc[m][n], 0, 0, 0);
        __builtin_amdgcn_s_setprio(0);
        __builtin_amdgcn_s_barrier();
        // ph2: (mi 4-7, ks0)
#pragma unroll
        for (int m = 0; m < 4; ++m) av[m] = RD(As, b, 0, wr * 128 + 64 + m * 16 + lo);
        if (pf) STAGEH(Bs, Bt, n0, nb, 0, I + 1);
        __builtin_amdgcn_s_setprio(1);
#pragma unroll
        for (int m = 0; m < 4; ++m)
#pragma unroll
            for (int n = 0; n < 4; ++n)
                acc[4 + m][n] = __builtin_amdgcn_mfma_f32_16x16x32_bf16(av[m], bv[n], acc[4 + m][n], 0, 0, 0);
        __builtin_amdgcn_s_setprio(0);
        if (pf) asm volatile("s_waitcnt vmcnt(4)" ::: "memory");
        else    asm volatile("s_waitcnt vmcnt(0)" ::: "memory");
        __builtin_amdgcn_s_barrier();
        // ph3: (mi 0-3, ks1)
#pragma unroll
        for (int n = 0; n < 4; ++n) bv[n] = RD(Bs, b, 1, wc * 64 + n * 16 + lo);
#pragma unroll
        for (int m = 0; m < 4; ++m) av[m] = RD(As, b, 1, wr * 128 + m * 16 + lo);
        if (pf) STAGEH(As, A, m0, nb, 1, I + 1);
        __builtin_amdgcn_s_setprio(1);
#pragma unroll
        for (int m = 0; m < 4; ++m)
#pragma unroll
            for (int n = 0; n < 4; ++n)
                acc[m][n] = __builtin_amdgcn_mfma_f32_16x16x32_bf16(av[m], bv[n], acc[m][n], 0, 0, 0);
        __builtin_amdgcn_s_setprio(0);
        __builtin_amdgcn_s_barrier();
        // ph4: (mi 4-7, ks1)
#pragma unroll
        for (int m = 0; m < 4; ++m) av[m] = RD(As, b, 1, wr * 128 + 64 + m * 16 + lo);
        if (pf) STAGEH(Bs, Bt, n0, nb, 1, I + 1);
        __builtin_amdgcn_s_setprio(1);
#pragma unroll
        for (int m = 0; m < 4; ++m)
#pragma unroll
            for (int n = 0; n < 4; ++n)
                acc[4 + m][n] = __builtin_amdgcn_mfma_f32_16x16x32_bf16(av[m], bv[n], acc[4 + m][n], 0, 0, 0);
        __builtin_amdgcn_s_setprio(0);
    }

    // ---- epilogue ----
#pragma unroll
    for (int mi = 0; mi < 8; ++mi)
#pragma unroll
        for (int ni = 0; ni < 4; ++ni) {
            const int col = n0 + wc * 64 + ni * 16 + lo;
            const float bsv = bias[col];
#pragma unroll
            for (int r = 0; r < 4; ++r) {
                const int row = m0 + wr * 128 + mi * 16 + hi * 4 + r;
                float vacc = acc[mi][ni][r] + bsv;
                if (EPI == 0) {
                    // fused RoPE on q,k: partner elem (col^1) lives in lane^1, same (mi,ni,r)
                    const float partner = __shfl_xor(vacc, 1);
                    const int sq = col >> 10;
                    if (sq < 2) {
                        const int d = col & 63;
                        const int nn2 = row & 2047;
                        float2 cs = tab[nn2 * 32 + (d >> 1)];
                        vacc = vacc * cs.x + ((d & 1) ? partner * cs.y : -partner * cs.y);
                    }
                    const int rem = col & 1023, hh = rem >> 6, dd = rem & 63;
                    const int bb = row >> 11, nn = row & 2047;
                    ((u16*)outp)[((((size_t)sq * B_ + bb) * H_ + hh) * N_ + nn) * D_ + dd] = f2b(vacc);
                } else {
                    const float gv = 0.5f * vacc * (1.f + erff(vacc * 0.70710678118f));
                    ((u16*)outp)[(size_t)row * Ndim + col] = f2b(gv);
                }
            }
        }
}

// ---------------- MFMA flash attention: dbuf, 1 barrier/tile (R21-proven) ------------------
#define SCL_LOG2E 0.1803368801111244f   // (1/sqrt(64)) * log2(e)
#define FIXEDM    12.0f

__global__ __launch_bounds__(256) void attn_mfma(const u16* __restrict__ q,
                                                 const u16* __restrict__ k,
                                                 const u16* __restrict__ v,
                                                 u16* __restrict__ out) {
    __shared__ u16 Ks[2][64 * 64];    // [buf][key][dim], elem = key*64 + (d ^ ((key&7)<<3))
    __shared__ u16 Vt[2][64 * 64];    // [buf][dim][key], elem = dim*64 + (key ^ ((dim&7)<<3))
    __shared__ u16 Ps[4][32 * 64];    // per-wave P, elem = row*64 + (key ^ ((row&7)<<3))

    const int t    = threadIdx.x;
    const int w    = t >> 6;
    const int lane = t & 63;
    const int hi   = lane >> 4;
    const int lo   = lane & 15;
    const int2 lb  = xcd_swz(gridDim.x, gridDim.y);   // 4 complete heads per XCD -> KV L2-resident
    const int bh   = lb.y;
    const int r0g  = lb.x * 128 + w * 32;             // this wave's global q-row base

    const u16* qb = q + (size_t)bh * N_ * D_;
    const u16* kb = k + (size_t)bh * N_ * D_;
    const u16* vb = v + (size_t)bh * N_ * D_;

    // ---- Q A-frags in registers, pre-scaled by 0.125*log2e ----
    v8s qa[2][2];   // [mi][ks]
#pragma unroll
    for (int mi = 0; mi < 2; ++mi)
#pragma unroll
        for (int ks = 0; ks < 2; ++ks) {
            uint4 rq = *(const uint4*)&qb[(size_t)(r0g + mi * 16 + lo) * 64 + ks * 32 + hi * 8];
            u32 qs[4];
            qs[0] = scale2(rq.x, SCL_LOG2E); qs[1] = scale2(rq.y, SCL_LOG2E);
            qs[2] = scale2(rq.z, SCL_LOG2E); qs[3] = scale2(rq.w, SCL_LOG2E);
            qa[mi][ks] = *(v8s*)qs;
        }

    // all-ones bf16 B-frag for the l-sum MFMA
    u32 ones4[4] = {0x3F803F80u, 0x3F803F80u, 0x3F803F80u, 0x3F803F80u};
    const v8s ones = *(v8s*)ones4;

    const v4f vzero = {0.f, 0.f, 0.f, 0.f};
    const v4f cinit = {-FIXEDM, -FIXEDM, -FIXEDM, -FIXEDM};
    v4f o_acc[2][4];                  // [mi][ni(dim)] -> rows hi*4+r, dims lo+16ni
    v4f l_acc[2];                     // [mi] -> row sums of P (replicated over cols)
#pragma unroll
    for (int mi = 0; mi < 2; ++mi) {
        l_acc[mi] = vzero;
#pragma unroll
        for (int ni = 0; ni < 4; ++ni) o_acc[mi][ni] = vzero;
    }

    // V-stage thread mapping: key-pair p, dim-group g
    const int vp = t & 31, vg = t >> 5;             // p: 0..31, g: 0..7
    const int vd0 = vg * 8, vkey = vp * 2;

    // K staging: direct global->LDS, source pre-swizzled (chunk ^= key&7), dest linear.
    auto KSTAGE = [&](int buf, int kt) {
#pragma unroll
        for (int j = 0; j < 2; ++j) {
            const int c = (w * 2 + j) * 64 + lane;
            const int key = c >> 3, ch = c & 7;
            gload_lds16(&kb[(size_t)(kt * 64 + key) * 64 + ((ch ^ (key & 7)) * 8)],
                        &Ks[buf][(w * 2 + j) * 512]);
        }
    };
    // V: register staging + transpose at write
    uint4 vr0, vr1;
    auto LOADV = [&](int kt) {
        vr0 = *(const uint4*)&vb[(size_t)(kt * 64 + vkey) * 64 + vd0];
        vr1 = *(const uint4*)&vb[(size_t)(kt * 64 + vkey + 1) * 64 + vd0];
    };
    auto WRITEV = [&](int buf) {
        const u32* a0 = (const u32*)&vr0;
        const u32* a1 = (const u32*)&vr1;
#pragma unroll
        for (int j = 0; j < 8; ++j) {
            u32 lo16 = (j & 1) ? (a0[j >> 1] >> 16) : (a0[j >> 1] & 0xffffu);
            u32 hi16 = (j & 1) ? (a1[j >> 1] >> 16) : (a1[j >> 1] & 0xffffu);
            u32 val = lo16 | (hi16 << 16);
            *(u32*)&Vt[buf][(vd0 + j) * 64 + (vkey ^ (j << 3))] = val;
        }
    };

    // prologue: tile 0 -> buf 0
    KSTAGE(0, 0);
    LOADV(0);
    WRITEV(0);
    __syncthreads();                  // drains vmcnt (K landed) + lgkm (V written)

    for (int kt = 0; kt < N_ / 64; ++kt) {
        const int cb = kt & 1;
        const bool pf = (kt + 1 < N_ / 64);
        if (pf) { KSTAGE(cb ^ 1, kt + 1); LOADV(kt + 1); }   // in flight during compute

        // ---- QK^T: S[mi][ni], accumulator seeded with -FIXEDM ----
        v4f s[2][4];
#pragma unroll
        for (int mi = 0; mi < 2; ++mi)
#pragma unroll
            for (int ni = 0; ni < 4; ++ni) s[mi][ni] = cinit;
        __builtin_amdgcn_s_setprio(1);
#pragma unroll
        for (int ks = 0; ks < 2; ++ks)
#pragma unroll
            for (int ni = 0; ni < 4; ++ni) {
                const int key = lo + 16 * ni;
                v8s bv = *(const v8s*)&Ks[cb][key * 64 + ((ks * 32 + hi * 8) ^ ((key & 7) << 3))];
                s[0][ni] = __builtin_amdgcn_mfma_f32_16x16x32_bf16(qa[0][ks], bv, s[0][ni], 0, 0, 0);
                s[1][ni] = __builtin_amdgcn_mfma_f32_16x16x32_bf16(qa[1][ks], bv, s[1][ni], 0, 0, 0);
            }
        __builtin_amdgcn_s_setprio(0);

        // ---- P = exp2(s): shift already inside the accumulator ----
#pragma unroll
        for (int mi = 0; mi < 2; ++mi)
#pragma unroll
            for (int ni = 0; ni < 4; ++ni)
#pragma unroll
                for (int r = 0; r < 4; ++r)
                    s[mi][ni][r] = exp2f(s[mi][ni][r]);

        // ---- per ks-half: pack cols [half*32, half*32+32) -> read pa -> PV half ----
#pragma unroll
        for (int half = 0; half < 2; ++half) {
#pragma unroll
            for (int mi = 0; mi < 2; ++mi)
#pragma unroll
                for (int f = 2 * half; f < 2 * half + 2; ++f)
#pragma unroll
                    for (int rp = 0; rp < 2; ++rp) {
                        u32 pk;
                        asm("v_cvt_pk_bf16_f32 %0, %1, %2"
                            : "=v"(pk) : "v"(s[mi][f][2 * rp]), "v"(s[mi][f][2 * rp + 1]));
                        const int row0 = mi * 16 + hi * 4 + 2 * rp;
                        const int row1 = row0 + 1;
                        Ps[w][row0 * 64 + ((lo + 16 * f) ^ ((row0 & 7) << 3))] = (u16)pk;
                        Ps[w][row1 * 64 + ((lo + 16 * f) ^ ((row1 & 7) << 3))] = (u16)(pk >> 16);
                    }
            v8s pa[2];
#pragma unroll
            for (int mi = 0; mi < 2; ++mi) {
                const int row = mi * 16 + lo;
                pa[mi] = *(const v8s*)&Ps[w][row * 64 + ((half * 32 + hi * 8) ^ ((lo & 7) << 3))];
            }
            __builtin_amdgcn_s_setprio(1);
#pragma unroll
            for (int ni = 0; ni < 4; ++ni) {
                const int dim = lo + 16 * ni;
                v8s vv = *(const v8s*)&Vt[cb][dim * 64 + ((half * 32 + hi * 8) ^ ((dim & 7) << 3))];
                o_acc[0][ni] = __builtin_amdgcn_mfma_f32_16x16x32_bf16(pa[0], vv, o_acc[0][ni], 0, 0, 0);
                o_acc[1][ni] = __builtin_amdgcn_mfma_f32_16x16x32_bf16(pa[1], vv, o_acc[1][ni], 0, 0, 0);
            }
            l_acc[0] = __builtin_amdgcn_mfma_f32_16x16x32_bf16(pa[0], ones, l_acc[0], 0, 0, 0);
            l_acc[1] = __builtin_amdgcn_mfma_f32_16x16x32_bf16(pa[1], ones, l_acc[1], 0, 0, 0);
            __builtin_amdgcn_s_setprio(0);
        }

        // ---- stage V(kt+1) into the buffer we did NOT read this iter ----
        if (pf) WRITEV(cb ^ 1);
        __syncthreads();              // orders K-gload + V-write (kt+1) -> reads (kt+1)
    }

    // ---- epilogue: normalize, store (B,N,C) bf16 ----
    const int bb = bh >> 4, hh = bh & 15;
#pragma unroll
    for (int mi = 0; mi < 2; ++mi)
#pragma unroll
        for (int r = 0; r < 4; ++r) {
            const float inv = 1.f / l_acc[mi][r];
            const int n = r0g + mi * 16 + hi * 4 + r;
#pragma unroll
            for (int ni = 0; ni < 4; ++ni) {
                out[((size_t)bb * N_ + n) * C_ + hh * D_ + lo + 16 * ni] = f2b(o_acc[mi][ni][r] * inv);
            }
        }
}

// ---------------- orchestration ----------------
// Workspace layout (overlapped lifetimes; total ~80.5 MB):
//   Region A (24 MB): Wtqkv | Wtproj | Wtfc1 | Wtfc2          [live: whole launch]
//   Region B (32 MB): qkv(24)  [prologue -> attn]   ... then a1(32)  [fc1 -> fc2]
//   Region C ( 8 MB): h1 [prologue -> qkvGEMM] -> oatt [attn -> proj] -> h2 [ln2 -> fc1]
//   Region D (16 MB): x1 [proj -> end]
//   Region E (0.5MB): tab
extern "C" void kernel_launch(void* const* d_in, const int* in_sizes, int n_in,
                              void* d_out, int out_size, void* d_ws, size_t ws_size,
                              hipStream_t stream) {
    (void)in_sizes; (void)n_in; (void)out_size; (void)ws_size;
    const float* x     = (const float*)d_in[0];
    const float* ln1g  = (const float*)d_in[1];
    const float* ln1b  = (const float*)d_in[2];
    const float* Wqkv  = (const float*)d_in[3];
    const float* bqkv  = (const float*)d_in[4];
    const float* Wproj = (const float*)d_in[5];
    const float* bproj = (const float*)d_in[6];
    const float* ln2g  = (const float*)d_in[7];
    const float* ln2b  = (const float*)d_in[8];
    const float* Wfc1  = (const float*)d_in[9];
    const float* bfc1  = (const float*)d_in[10];
    const float* Wfc2  = (const float*)d_in[11];
    const float* bfc2  = (const float*)d_in[12];
    float* out = (float*)d_out;

    char* base = (char*)d_ws;
    const size_t MB = 1024 * 1024;
    // Region A: weights (24 MB)
    u16* Wtqkv  = (u16*)(base);                    // 6 MB
    u16* Wtproj = (u16*)(base + 6 * MB);           // 2 MB
    u16* Wtfc1  = (u16*)(base + 8 * MB);           // 8 MB
    u16* Wtfc2  = (u16*)(base + 16 * MB);          // 8 MB
    // Region B: 32 MB at +24 MB
    u16* qkv    = (u16*)(base + 24 * MB);          // 24 MB  (3,B,H,N,D) bf16
    u16* a1     = (u16*)(base + 24 * MB);          // 32 MB  gelu(fc1), overlays qkv
    // Region C: 8 MB at +56 MB
    u16* h1     = (u16*)(base + 56 * MB);          // LN1 out bf16
    u16* oatt   = (u16*)(base + 56 * MB);          // attn out, overlays h1
    u16* h2     = (u16*)(base + 56 * MB);          // LN2 out, overlays oatt
    // Region D: 16 MB at +64 MB
    float* x1   = (float*)(base + 64 * MB);        // residual after attn, fp32
    // Region E: tab at +80 MB
    float2* tab = (float2*)(base + 80 * MB);       // 0.5 MB

    transpose_all<<<16640, 256, 0, stream>>>(Wqkv, Wproj, Wfc1, Wfc2,
                                             Wtqkv, Wtproj, Wtfc1, Wtfc2, tab,
                                             x, ln1g, ln1b, h1);
    gemm256<0><<<dim3(3 * C_ / 256, M_ / 256), 512, 0, stream>>>(h1, Wtqkv, bqkv, qkv, tab, 3 * C_, C_);
    attn_mfma<<<dim3(N_ / 128, B_ * H_), 256, 0, stream>>>(
        qkv, qkv + (size_t)B_ * H_ * N_ * D_, qkv + (size_t)2 * B_ * H_ * N_ * D_, oatt);
    gemm_bk64<<<dim3(C_ / 128, M_ / 64), 256, 0, stream>>>(oatt, Wtproj, bproj, x1, x, C_, C_);
    ln_kernel<<<M_, 256, 0, stream>>>(x1, ln2g, ln2b, h2);
    gemm256<2><<<dim3(HID_ / 256, M_ / 256), 512, 0, stream>>>(h2, Wtfc1, bfc1, a1, nullptr, HID_, C_);
    gemm_bk64<<<dim3(C_ / 128, M_ / 64), 256, 0, stream>>>(a1, Wtfc2, bfc2, out, x1, C_, HID_);
}

// Round 24
// 273.353 us; speedup vs baseline: 1.0491x; 1.0491x over previous
//
#include <hip/hip_runtime.h>
#include <cstdint>
#include <cstddef>

typedef unsigned short u16;
typedef unsigned int   u32;
typedef __attribute__((ext_vector_type(8))) short v8s;   // 8 bf16 (4 VGPRs) MFMA A/B frag
typedef __attribute__((ext_vector_type(4))) float v4f;   // 4 fp32 MFMA C/D frag

// Fixed problem shape
#define B_   2
#define N_   2048
#define C_   1024
#define H_   16
#define D_   64
#define HID_ 4096
#define M_   4096   // B_*N_

static __device__ __forceinline__ float b2f(u32 u) {
    union { u32 i; float f; } x; x.i = u << 16; return x.f;
}
static __device__ __forceinline__ u16 f2b(float f) {
    union { float f; u32 i; } x; x.f = f;
    u32 r = (x.i + 0x7fffu + ((x.i >> 16) & 1u)) >> 16;
    return (u16)r;
}
static __device__ __forceinline__ u32 scale2(u32 raw, float s) {
    float lo = b2f(raw & 0xffffu) * s, hi = b2f(raw >> 16) * s;
    return (u32)f2b(lo) | ((u32)f2b(hi) << 16);
}

// async global->LDS, 16B per lane; LDS dest is wave-uniform base + lane*16
static __device__ __forceinline__ void gload_lds16(const u16* g, u16* l) {
    __builtin_amdgcn_global_load_lds(
        (const __attribute__((address_space(1))) void*)g,
        (__attribute__((address_space(3))) void*)l,
        16, 0, 0);
}

// T1 XCD-aware block swizzle: physical linear id -> logical (x,y); nwg must be %8==0
static __device__ __forceinline__ int2 xcd_swz(int gx, int gy) {
    const int nwg = gx * gy;
    int id = blockIdx.y * gx + blockIdx.x;
    id = (id & 7) * (nwg >> 3) + (id >> 3);
    return make_int2(id % gx, id / gx);
}

// ---------------- fused prologue: weight transpose/cvt + RoPE table + LN1, one launch ------
// ids 0..12287: 32x32 transpose tiles; 12288..12543: cos/sin table; 12544..16639: LN1 rows.
__global__ __launch_bounds__(256) void transpose_all(const float* __restrict__ Wqkv,
                                                     const float* __restrict__ Wproj,
                                                     const float* __restrict__ Wfc1,
                                                     const float* __restrict__ Wfc2,
                                                     u16* __restrict__ Oqkv,
                                                     u16* __restrict__ Oproj,
                                                     u16* __restrict__ Ofc1,
                                                     u16* __restrict__ Ofc2,
                                                     float2* __restrict__ tab,
                                                     const float* __restrict__ xin,
                                                     const float* __restrict__ ln1g,
                                                     const float* __restrict__ ln1b,
                                                     u16* __restrict__ h1out) {
    __shared__ float tile[32][33];
    __shared__ float ps[4], psq[4], stats[2];
    int id = blockIdx.x;
    const int t = threadIdx.x;
    if (id >= 12544) {                 // ---- LN1 row (fp32 x -> bf16 h1) ----
        const int row = id - 12544;
        float4 v = ((const float4*)xin)[(size_t)row * 256 + t];
        float s  = v.x + v.y + v.z + v.w;
        float sq = v.x * v.x + v.y * v.y + v.z * v.z + v.w * v.w;
#pragma unroll
        for (int off = 32; off > 0; off >>= 1) { s += __shfl_down(s, off); sq += __shfl_down(sq, off); }
        if ((t & 63) == 0) { ps[t >> 6] = s; psq[t >> 6] = sq; }
        __syncthreads();
        if (t == 0) {
            float S = ps[0] + ps[1] + ps[2] + ps[3];
            float Q = psq[0] + psq[1] + psq[2] + psq[3];
            float mu  = S * (1.f / 1024.f);
            float var = Q * (1.f / 1024.f) - mu * mu;
            stats[0] = mu; stats[1] = rsqrtf(var + 1e-5f);
        }
        __syncthreads();
        const float mu = stats[0], istd = stats[1];
        float4 gg = ((const float4*)ln1g)[t];
        float4 bb = ((const float4*)ln1b)[t];
        ushort4 o;
        o.x = f2b((v.x - mu) * istd * gg.x + bb.x);
        o.y = f2b((v.y - mu) * istd * gg.y + bb.y);
        o.z = f2b((v.z - mu) * istd * gg.z + bb.z);
        o.w = f2b((v.w - mu) * istd * gg.w + bb.w);
        *(ushort4*)&h1out[(size_t)row * 1024 + t * 4] = o;
        return;
    }
    if (id >= 12288) {                 // ---- RoPE table ----
        const int i = (id - 12288) * 256 + t;
        const int d = i & 31, n = i >> 5;
        float inv = powf(10000.f, -(float)d * (1.f / 32.f));
        float fr = (float)n * inv;
        tab[i] = make_float2(cosf(fr), sinf(fr));
        return;
    }
    const float* in; u16* out; int K, N, nx;
    if (id < 3072)      { in = Wqkv;  out = Oqkv;  K = 1024; N = 3072; nx = 96;  }
    else if (id < 4096) { in = Wproj; out = Oproj; K = 1024; N = 1024; nx = 32;  id -= 3072; }
    else if (id < 8192) { in = Wfc1;  out = Ofc1;  K = 1024; N = 4096; nx = 128; id -= 4096; }
    else                { in = Wfc2;  out = Ofc2;  K = 4096; N = 1024; nx = 32;  id -= 8192; }
    const int n0 = (id % nx) * 32, k0 = (id / nx) * 32;
    const int c = t & 31, r8 = t >> 5;
#pragma unroll
    for (int i = 0; i < 4; ++i)
        tile[r8 + i * 8][c] = in[(size_t)(k0 + r8 + i * 8) * N + n0 + c];
    __syncthreads();
#pragma unroll
    for (int i = 0; i < 4; ++i)
        out[(size_t)(n0 + r8 + i * 8) * K + k0 + c] = f2b(tile[c][r8 + i * 8]);
}

// ---------------- LayerNorm: fp32 in -> bf16 out, one block per row (C=1024) ----------------
__global__ __launch_bounds__(256) void ln_kernel(const float* __restrict__ in,
                                                 const float* __restrict__ g,
                                                 const float* __restrict__ b,
                                                 u16* __restrict__ out) {
    __shared__ float ps[4], psq[4];
    __shared__ float stats[2];
    const int row = blockIdx.x;
    const int t = threadIdx.x;
    float4 v = ((const float4*)in)[(size_t)row * 256 + t];
    float s  = v.x + v.y + v.z + v.w;
    float sq = v.x * v.x + v.y * v.y + v.z * v.z + v.w * v.w;
#pragma unroll
    for (int off = 32; off > 0; off >>= 1) { s += __shfl_down(s, off); sq += __shfl_down(sq, off); }
    if ((t & 63) == 0) { ps[t >> 6] = s; psq[t >> 6] = sq; }
    __syncthreads();
    if (t == 0) {
        float S = ps[0] + ps[1] + ps[2] + ps[3];
        float Q = psq[0] + psq[1] + psq[2] + psq[3];
        float mu  = S * (1.f / 1024.f);
        float var = Q * (1.f / 1024.f) - mu * mu;
        stats[0] = mu; stats[1] = rsqrtf(var + 1e-5f);
    }
    __syncthreads();
    const float mu = stats[0], istd = stats[1];
    float4 gg = ((const float4*)g)[t];
    float4 bb = ((const float4*)b)[t];
    ushort4 o;
    o.x = f2b((v.x - mu) * istd * gg.x + bb.x);
    o.y = f2b((v.y - mu) * istd * gg.y + bb.y);
    o.z = f2b((v.z - mu) * istd * gg.z + bb.z);
    o.w = f2b((v.w - mu) * istd * gg.w + bb.w);
    *(ushort4*)&out[(size_t)row * 1024 + t * 4] = o;
}

// ---------------- MFMA GEMM (qkv): BM=128/BN=128/BK=32, 3-buffer counted vmcnt -------------
// R17-proven. EPI 0: qkv scatter to (3,B,H,N,D) bf16 with fused RoPE on q,k (partner=lane^1).
template <int EPI, int BM>
__global__ __launch_bounds__(256) void gemm_bt(const u16* __restrict__ A,
                                               const u16* __restrict__ Bt,
                                               const float* __restrict__ bias,
                                               void* __restrict__ outp,
                                               const float* __restrict__ resid,
                                               const float2* __restrict__ tab,
                                               int Ndim, int Kdim) {
    constexpr int NACC = (BM == 128) ? 4 : 2;   // B-frags per wave
    constexpr int AISS = BM / 64;               // A staging issues per wave
    __shared__ u16 As[3][BM * 32];
    __shared__ u16 Bs[3][128 * 32];
    const int t = threadIdx.x;
    const int lane = t & 63;
    const int w = t >> 6;
    const int wr = (BM == 128) ? (w >> 1) : 0;
    const int wc = (BM == 128) ? (w & 1) : w;
    const int2 lb = xcd_swz(gridDim.x, gridDim.y);
    const int m0 = lb.y * BM, n0 = lb.x * 128;
    const int hi = lane >> 4, lo = lane & 15;

    auto STAGE = [&](int buf, int kt) {
#pragma unroll
        for (int j = 0; j < AISS; ++j) {
            const int c = (w * AISS + j) * 64 + lane;
            gload_lds16(&A[(size_t)(m0 + (c >> 2)) * Kdim + kt + (c & 3) * 8],
                        &As[buf][(w * AISS + j) * 512]);
        }
#pragma unroll
        for (int j = 0; j < 2; ++j) {
            const int c = (w * 2 + j) * 64 + lane;
            gload_lds16(&Bt[(size_t)(n0 + (c >> 2)) * Kdim + kt + (c & 3) * 8],
                        &Bs[buf][(w * 2 + j) * 512]);
        }
    };

    const v4f vzero = {0.f, 0.f, 0.f, 0.f};
    v4f acc[4][NACC];
#pragma unroll
    for (int i = 0; i < 4; ++i)
#pragma unroll
        for (int j = 0; j < NACC; ++j) acc[i][j] = vzero;

    const int nt = Kdim / 32;
    STAGE(0, 0);
    STAGE(1, 32);
    for (int kt = 0; kt < nt; ++kt) {
        if (kt + 1 == nt) asm volatile("s_waitcnt vmcnt(0)" ::: "memory");
        else if constexpr (BM == 128) asm volatile("s_waitcnt vmcnt(4)" ::: "memory");
        else                          asm volatile("s_waitcnt vmcnt(3)" ::: "memory");
        __builtin_amdgcn_s_barrier();
        if (kt + 2 < nt) STAGE((kt + 2) % 3, (kt + 2) * 32);
        const int cur = kt % 3;
        v8s av[4], bv[NACC];
#pragma unroll
        for (int mi = 0; mi < 4; ++mi)
            av[mi] = *(const v8s*)&As[cur][(wr * 64 + mi * 16 + lo) * 32 + hi * 8];
#pragma unroll
        for (int ni = 0; ni < NACC; ++ni)
            bv[ni] = *(const v8s*)&Bs[cur][(wc * (NACC * 16) + ni * 16 + lo) * 32 + hi * 8];
#pragma unroll
        for (int mi = 0; mi < 4; ++mi)
#pragma unroll
            for (int ni = 0; ni < NACC; ++ni)
                acc[mi][ni] = __builtin_amdgcn_mfma_f32_16x16x32_bf16(av[mi], bv[ni], acc[mi][ni], 0, 0, 0);
    }

#pragma unroll
    for (int mi = 0; mi < 4; ++mi)
#pragma unroll
        for (int ni = 0; ni < NACC; ++ni) {
            const int col = n0 + wc * (NACC * 16) + ni * 16 + lo;
            const float bsv = bias[col];
#pragma unroll
            for (int r = 0; r < 4; ++r) {
                const int row = m0 + wr * 64 + mi * 16 + hi * 4 + r;
                float vacc = acc[mi][ni][r] + bsv;
                if (EPI == 0) {
                    // fused RoPE on q,k: partner elem (col^1) lives in lane^1, same (mi,ni,r)
                    const float partner = __shfl_xor(vacc, 1);
                    const int s = col >> 10;
                    if (s < 2) {
                        const int d = col & 63;
                        const int n = row & 2047;
                        float2 cs = tab[n * 32 + (d >> 1)];
                        vacc = vacc * cs.x + ((d & 1) ? partner * cs.y : -partner * cs.y);
                    }
                    const int rem = col & 1023, hh = rem >> 6, dd = rem & 63;
                    const int bb = row >> 11, nn = row & 2047;
                    ((u16*)outp)[((((size_t)s * B_ + bb) * H_ + hh) * N_ + nn) * D_ + dd] = f2b(vacc);
                } else if (EPI == 1) {
                    ((float*)outp)[(size_t)row * Ndim + col] = vacc + resid[(size_t)row * Ndim + col];
                } else {
                    const float gv = 0.5f * vacc * (1.f + erff(vacc * 0.70710678118f));
                    ((u16*)outp)[(size_t)row * Ndim + col] = f2b(gv);
                }
            }
        }
}

// ---------------- GEMM BM=64 x BN=128, BK=64, 3-buffer counted vmcnt (proj, fc2) -----------
__global__ __launch_bounds__(256) void gemm_bk64(const u16* __restrict__ A,
                                                 const u16* __restrict__ Bt,
                                                 const float* __restrict__ bias,
                                                 float* __restrict__ outp,
                                                 const float* __restrict__ resid,
                                                 int Ndim, int Kdim) {
    __shared__ u16 As[3][64 * 64];
    __shared__ u16 Bs[3][128 * 64];
    const int t = threadIdx.x;
    const int lane = t & 63;
    const int w = t >> 6;                 // wave = N-subtile (4 x 32 cols)
    const int2 lb = xcd_swz(gridDim.x, gridDim.y);
    const int m0 = lb.y * 64, n0 = lb.x * 128;
    const int hi = lane >> 4, lo = lane & 15;

    auto STAGE = [&](int buf, int kb) {
#pragma unroll
        for (int j = 0; j < 2; ++j) {     // A: 64 rows x 64 u16 = 512 chunks
            const int c = (w * 2 + j) * 64 + lane;
            const int row = c >> 3, ch = c & 7;
            gload_lds16(&A[(size_t)(m0 + row) * Kdim + kb + ((ch ^ (row & 7)) * 8)],
                        &As[buf][(w * 2 + j) * 512]);
        }
#pragma unroll
        for (int j = 0; j < 4; ++j) {     // B: 128 rows x 64 u16 = 1024 chunks
            const int c = (w * 4 + j) * 64 + lane;
            const int row = c >> 3, ch = c & 7;
            gload_lds16(&Bt[(size_t)(n0 + row) * Kdim + kb + ((ch ^ (row & 7)) * 8)],
                        &Bs[buf][(w * 4 + j) * 512]);
        }
    };

    const v4f vzero = {0.f, 0.f, 0.f, 0.f};
    v4f acc[4][2];
#pragma unroll
    for (int i = 0; i < 4; ++i) { acc[i][0] = vzero; acc[i][1] = vzero; }

    const int nt = Kdim / 64;
    STAGE(0, 0);
    STAGE(1, 64);
    for (int kt = 0; kt < nt; ++kt) {
        if (kt + 1 == nt) asm volatile("s_waitcnt vmcnt(0)" ::: "memory");
        else              asm volatile("s_waitcnt vmcnt(6)" ::: "memory");
        __builtin_amdgcn_s_barrier();
        if (kt + 2 < nt) STAGE((kt + 2) % 3, (kt + 2) * 64);
        const int cur = kt % 3;
#pragma unroll
        for (int ks = 0; ks < 2; ++ks) {
            v8s av[4], bv[2];
#pragma unroll
            for (int m = 0; m < 4; ++m) {
                const int row = m * 16 + lo;
                av[m] = *(const v8s*)&As[cur][row * 64 + (((ks * 4 + hi) ^ (row & 7)) * 8)];
            }
#pragma unroll
            for (int n = 0; n < 2; ++n) {
                const int row = w * 32 + n * 16 + lo;
                bv[n] = *(const v8s*)&Bs[cur][row * 64 + (((ks * 4 + hi) ^ (row & 7)) * 8)];
            }
#pragma unroll
            for (int m = 0; m < 4; ++m)
#pragma unroll
                for (int n = 0; n < 2; ++n)
                    acc[m][n] = __builtin_amdgcn_mfma_f32_16x16x32_bf16(av[m], bv[n], acc[m][n], 0, 0, 0);
        }
    }

#pragma unroll
    for (int m = 0; m < 4; ++m)
#pragma unroll
        for (int n = 0; n < 2; ++n) {
            const int col = n0 + w * 32 + n * 16 + lo;
            const float bsv = bias[col];
#pragma unroll
            for (int r = 0; r < 4; ++r) {
                const int row = m0 + m * 16 + hi * 4 + r;
                outp[(size_t)row * Ndim + col] = acc[m][n][r] + bsv + resid[(size_t)row * Ndim + col];
            }
        }
}

// ---------------- 256x256 8-wave GEMM, 4 phases/K-tile, counted vmcnt, GELU epilogue --------
__global__ __launch_bounds__(512, 2) void gemm256_gelu(const u16* __restrict__ A,
                                                       const u16* __restrict__ Bt,
                                                       const float* __restrict__ bias,
                                                       u16* __restrict__ outp,
                                                       int Ndim, int Kdim) {
    __shared__ u16 As[2 * 2 * 256 * 32];   // [buf][ks][row][32]
    __shared__ u16 Bs[2 * 2 * 256 * 32];
    const int t = threadIdx.x;             // 0..511
    const int lane = t & 63;
    const int w = t >> 6;                  // 0..7
    const int wr = w >> 2, wc = w & 3;     // 2 x 4 wave grid; per-wave out 128x64
    const int hi = lane >> 4, lo = lane & 15;
    const int2 lb = xcd_swz(gridDim.x, gridDim.y);
    const int m0 = lb.y * 256, n0 = lb.x * 256;
    const int koff = (hi ^ ((lo >> 1) & 3)) * 8;   // swizzled k-chunk for frag reads

    auto STAGEH = [&](u16* lds, const u16* src, int rb, int b, int ks, int kt) {
#pragma unroll
        for (int j = 0; j < 2; ++j) {
            const int c = j * 512 + t;         // 16B chunk id, 0..1023
            const int row = c >> 2;
            const int ch = c & 3;
            gload_lds16(&src[(size_t)(rb + row) * Kdim + kt * 64 + ks * 32 +
                             ((ch ^ ((row >> 1) & 3)) * 8)],
                        &lds[(b * 2 + ks) * 8192 + c * 8]);
        }
    };
    auto RD = [&](const u16* lds, int b, int ks, int row) -> v8s {
        return *(const v8s*)&lds[(b * 2 + ks) * 8192 + row * 32 + koff];
    };

    const v4f vzero = {0.f, 0.f, 0.f, 0.f};
    v4f acc[8][4];
#pragma unroll
    for (int i = 0; i < 8; ++i)
#pragma unroll
        for (int j = 0; j < 4; ++j) acc[i][j] = vzero;

    const int nt = Kdim / 64;
    STAGEH(As, A, m0, 0, 0, 0);
    STAGEH(Bs, Bt, n0, 0, 0, 0);
    STAGEH(As, A, m0, 0, 1, 0);
    STAGEH(Bs, Bt, n0, 0, 1, 0);

    for (int I = 0; I < nt; ++I) {
        const int b = I & 1, nb = b ^ 1;
        const bool pf = (I + 1 < nt);
        v8s av[4], bv[4];
        if (pf) asm volatile("s_waitcnt vmcnt(4)" ::: "memory");
        else    asm volatile("s_waitcnt vmcnt(2)" ::: "memory");
        __builtin_amdgcn_s_barrier();
        // ph1: (mi 0-3, ks0)
#pragma unroll
        for (int n = 0; n < 4; ++n) bv[n] = RD(Bs, b, 0, wc * 64 + n * 16 + lo);
#pragma unroll
        for (int m = 0; m < 4; ++m) av[m] = RD(As, b, 0, wr * 128 + m * 16 + lo);
        if (pf) STAGEH(As, A, m0, nb, 0, I + 1);
        __builtin_amdgcn_s_setprio(1);
#pragma unroll
        for (int m = 0; m < 4; ++m)
#pragma unroll
            for (int n = 0; n < 4; ++n)
                acc[m][n] = __builtin_amdgcn_mfma_f32_16x16x32_bf16(av[m], bv[n], acc[m][n], 0, 0, 0);
        __builtin_amdgcn_s_setprio(0);
        __builtin_amdgcn_s_barrier();
        // ph2: (mi 4-7, ks0)
#pragma unroll
        for (int m = 0; m < 4; ++m) av[m] = RD(As, b, 0, wr * 128 + 64 + m * 16 + lo);
        if (pf) STAGEH(Bs, Bt, n0, nb, 0, I + 1);
        __builtin_amdgcn_s_setprio(1);
#pragma unroll
        for (int m = 0; m < 4; ++m)
#pragma unroll
            for (int n = 0; n < 4; ++n)
                acc[4 + m][n] = __builtin_amdgcn_mfma_f32_16x16x32_bf16(av[m], bv[n], acc[4 + m][n], 0, 0, 0);
        __builtin_amdgcn_s_setprio(0);
        if (pf) asm volatile("s_waitcnt vmcnt(4)" ::: "memory");
        else    asm volatile("s_waitcnt vmcnt(0)" ::: "memory");
        __builtin_amdgcn_s_barrier();
        // ph3: (mi 0-3, ks1)
#pragma unroll
        for (int n = 0; n < 4; ++n) bv[n] = RD(Bs, b, 1, wc * 64 + n * 16 + lo);
#pragma unroll
        for (int m = 0; m < 4; ++m) av[m] = RD(As, b, 1, wr * 128 + m * 16 + lo);
        if (pf) STAGEH(As, A, m0, nb, 1, I + 1);
        __builtin_amdgcn_s_setprio(1);
#pragma unroll
        for (int m = 0; m < 4; ++m)
#pragma unroll
            for (int n = 0; n < 4; ++n)
                acc[m][n] = __builtin_amdgcn_mfma_f32_16x16x32_bf16(av[m], bv[n], acc[m][n], 0, 0, 0);
        __builtin_amdgcn_s_setprio(0);
        __builtin_amdgcn_s_barrier();
        // ph4: (mi 4-7, ks1)
#pragma unroll
        for (int m = 0; m < 4; ++m) av[m] = RD(As, b, 1, wr * 128 + 64 + m * 16 + lo);
        if (pf) STAGEH(Bs, Bt, n0, nb, 1, I + 1);
        __builtin_amdgcn_s_setprio(1);
#pragma unroll
        for (int m = 0; m < 4; ++m)
#pragma unroll
            for (int n = 0; n < 4; ++n)
                acc[4 + m][n] = __builtin_amdgcn_mfma_f32_16x16x32_bf16(av[m], bv[n], acc[4 + m][n], 0, 0, 0);
        __builtin_amdgcn_s_setprio(0);
    }

    // ---- epilogue: bias + exact GELU -> bf16 ----
#pragma unroll
    for (int mi = 0; mi < 8; ++mi)
#pragma unroll
        for (int ni = 0; ni < 4; ++ni) {
            const int col = n0 + wc * 64 + ni * 16 + lo;
            const float bsv = bias[col];
#pragma unroll
            for (int r = 0; r < 4; ++r) {
                const int row = m0 + wr * 128 + mi * 16 + hi * 4 + r;
                float vacc = acc[mi][ni][r] + bsv;
                const float gv = 0.5f * vacc * (1.f + erff(vacc * 0.70710678118f));
                outp[(size_t)row * Ndim + col] = f2b(gv);
            }
        }
}

// ---------------- MFMA flash attention: dbuf, 1 barrier/tile (R21-proven) ------------------
#define SCL_LOG2E 0.1803368801111244f   // (1/sqrt(64)) * log2(e)
#define FIXEDM    12.0f

__global__ __launch_bounds__(256) void attn_mfma(const u16* __restrict__ q,
                                                 const u16* __restrict__ k,
                                                 const u16* __restrict__ v,
                                                 u16* __restrict__ out) {
    __shared__ u16 Ks[2][64 * 64];    // [buf][key][dim], elem = key*64 + (d ^ ((key&7)<<3))
    __shared__ u16 Vt[2][64 * 64];    // [buf][dim][key], elem = dim*64 + (key ^ ((dim&7)<<3))
    __shared__ u16 Ps[4][32 * 64];    // per-wave P, elem = row*64 + (key ^ ((row&7)<<3))

    const int t    = threadIdx.x;
    const int w    = t >> 6;
    const int lane = t & 63;
    const int hi   = lane >> 4;
    const int lo   = lane & 15;
    const int2 lb  = xcd_swz(gridDim.x, gridDim.y);   // 4 complete heads per XCD -> KV L2-resident
    const int bh   = lb.y;
    const int r0g  = lb.x * 128 + w * 32;             // this wave's global q-row base

    const u16* qb = q + (size_t)bh * N_ * D_;
    const u16* kb = k + (size_t)bh * N_ * D_;
    const u16* vb = v + (size_t)bh * N_ * D_;

    // ---- Q A-frags in registers, pre-scaled by 0.125*log2e ----
    v8s qa[2][2];   // [mi][ks]
#pragma unroll
    for (int mi = 0; mi < 2; ++mi)
#pragma unroll
        for (int ks = 0; ks < 2; ++ks) {
            uint4 rq = *(const uint4*)&qb[(size_t)(r0g + mi * 16 + lo) * 64 + ks * 32 + hi * 8];
            u32 qs[4];
            qs[0] = scale2(rq.x, SCL_LOG2E); qs[1] = scale2(rq.y, SCL_LOG2E);
            qs[2] = scale2(rq.z, SCL_LOG2E); qs[3] = scale2(rq.w, SCL_LOG2E);
            qa[mi][ks] = *(v8s*)qs;
        }

    // all-ones bf16 B-frag for the l-sum MFMA
    u32 ones4[4] = {0x3F803F80u, 0x3F803F80u, 0x3F803F80u, 0x3F803F80u};
    const v8s ones = *(v8s*)ones4;

    const v4f vzero = {0.f, 0.f, 0.f, 0.f};
    const v4f cinit = {-FIXEDM, -FIXEDM, -FIXEDM, -FIXEDM};
    v4f o_acc[2][4];                  // [mi][ni(dim)] -> rows hi*4+r, dims lo+16ni
    v4f l_acc[2];                     // [mi] -> row sums of P (replicated over cols)
#pragma unroll
    for (int mi = 0; mi < 2; ++mi) {
        l_acc[mi] = vzero;
#pragma unroll
        for (int ni = 0; ni < 4; ++ni) o_acc[mi][ni] = vzero;
    }

    // V-stage thread mapping: key-pair p, dim-group g
    const int vp = t & 31, vg = t >> 5;             // p: 0..31, g: 0..7
    const int vd0 = vg * 8, vkey = vp * 2;

    // K staging: direct global->LDS, source pre-swizzled (chunk ^= key&7), dest linear.
    auto KSTAGE = [&](int buf, int kt) {
#pragma unroll
        for (int j = 0; j < 2; ++j) {
            const int c = (w * 2 + j) * 64 + lane;
            const int key = c >> 3, ch = c & 7;
            gload_lds16(&kb[(size_t)(kt * 64 + key) * 64 + ((ch ^ (key & 7)) * 8)],
                        &Ks[buf][(w * 2 + j) * 512]);
        }
    };
    // V: register staging + transpose at write
    uint4 vr0, vr1;
    auto LOADV = [&](int kt) {
        vr0 = *(const uint4*)&vb[(size_t)(kt * 64 + vkey) * 64 + vd0];
        vr1 = *(const uint4*)&vb[(size_t)(kt * 64 + vkey + 1) * 64 + vd0];
    };
    auto WRITEV = [&](int buf) {
        const u32* a0 = (const u32*)&vr0;
        const u32* a1 = (const u32*)&vr1;
#pragma unroll
        for (int j = 0; j < 8; ++j) {
            u32 lo16 = (j & 1) ? (a0[j >> 1] >> 16) : (a0[j >> 1] & 0xffffu);
            u32 hi16 = (j & 1) ? (a1[j >> 1] >> 16) : (a1[j >> 1] & 0xffffu);
            u32 val = lo16 | (hi16 << 16);
            *(u32*)&Vt[buf][(vd0 + j) * 64 + (vkey ^ (j << 3))] = val;
        }
    };

    // prologue: tile 0 -> buf 0
    KSTAGE(0, 0);
    LOADV(0);
    WRITEV(0);
    __syncthreads();                  // drains vmcnt (K landed) + lgkm (V written)

    for (int kt = 0; kt < N_ / 64; ++kt) {
        const int cb = kt & 1;
        const bool pf = (kt + 1 < N_ / 64);
        if (pf) { KSTAGE(cb ^ 1, kt + 1); LOADV(kt + 1); }   // in flight during compute

        // ---- QK^T: S[mi][ni], accumulator seeded with -FIXEDM ----
        v4f s[2][4];
#pragma unroll
        for (int mi = 0; mi < 2; ++mi)
#pragma unroll
            for (int ni = 0; ni < 4; ++ni) s[mi][ni] = cinit;
        __builtin_amdgcn_s_setprio(1);
#pragma unroll
        for (int ks = 0; ks < 2; ++ks)
#pragma unroll
            for (int ni = 0; ni < 4; ++ni) {
                const int key = lo + 16 * ni;
                v8s bv = *(const v8s*)&Ks[cb][key * 64 + ((ks * 32 + hi * 8) ^ ((key & 7) << 3))];
                s[0][ni] = __builtin_amdgcn_mfma_f32_16x16x32_bf16(qa[0][ks], bv, s[0][ni], 0, 0, 0);
                s[1][ni] = __builtin_amdgcn_mfma_f32_16x16x32_bf16(qa[1][ks], bv, s[1][ni], 0, 0, 0);
            }
        __builtin_amdgcn_s_setprio(0);

        // ---- P = exp2(s): shift already inside the accumulator ----
#pragma unroll
        for (int mi = 0; mi < 2; ++mi)
#pragma unroll
            for (int ni = 0; ni < 4; ++ni)
#pragma unroll
                for (int r = 0; r < 4; ++r)
                    s[mi][ni][r] = exp2f(s[mi][ni][r]);

        // ---- per ks-half: pack cols [half*32, half*32+32) -> read pa -> PV half ----
#pragma unroll
        for (int half = 0; half < 2; ++half) {
#pragma unroll
            for (int mi = 0; mi < 2; ++mi)
#pragma unroll
                for (int f = 2 * half; f < 2 * half + 2; ++f)
#pragma unroll
                    for (int rp = 0; rp < 2; ++rp) {
                        u32 pk;
                        asm("v_cvt_pk_bf16_f32 %0, %1, %2"
                            : "=v"(pk) : "v"(s[mi][f][2 * rp]), "v"(s[mi][f][2 * rp + 1]));
                        const int row0 = mi * 16 + hi * 4 + 2 * rp;
                        const int row1 = row0 + 1;
                        Ps[w][row0 * 64 + ((lo + 16 * f) ^ ((row0 & 7) << 3))] = (u16)pk;
                        Ps[w][row1 * 64 + ((lo + 16 * f) ^ ((row1 & 7) << 3))] = (u16)(pk >> 16);
                    }
            v8s pa[2];
#pragma unroll
            for (int mi = 0; mi < 2; ++mi) {
                const int row = mi * 16 + lo;
                pa[mi] = *(const v8s*)&Ps[w][row * 64 + ((half * 32 + hi * 8) ^ ((lo & 7) << 3))];
            }
            __builtin_amdgcn_s_setprio(1);
#pragma unroll
            for (int ni = 0; ni < 4; ++ni) {
                const int dim = lo + 16 * ni;
                v8s vv = *(const v8s*)&Vt[cb][dim * 64 + ((half * 32 + hi * 8) ^ ((dim & 7) << 3))];
                o_acc[0][ni] = __builtin_amdgcn_mfma_f32_16x16x32_bf16(pa[0], vv, o_acc[0][ni], 0, 0, 0);
                o_acc[1][ni] = __builtin_amdgcn_mfma_f32_16x16x32_bf16(pa[1], vv, o_acc[1][ni], 0, 0, 0);
            }
            l_acc[0] = __builtin_amdgcn_mfma_f32_16x16x32_bf16(pa[0], ones, l_acc[0], 0, 0, 0);
            l_acc[1] = __builtin_amdgcn_mfma_f32_16x16x32_bf16(pa[1], ones, l_acc[1], 0, 0, 0);
            __builtin_amdgcn_s_setprio(0);
        }

        // ---- stage V(kt+1) into the buffer we did NOT read this iter ----
        if (pf) WRITEV(cb ^ 1);
        __syncthreads();              // orders K-gload + V-write (kt+1) -> reads (kt+1)
    }

    // ---- epilogue: normalize, store (B,N,C) bf16 ----
    const int bb = bh >> 4, hh = bh & 15;
#pragma unroll
    for (int mi = 0; mi < 2; ++mi)
#pragma unroll
        for (int r = 0; r < 4; ++r) {
            const float inv = 1.f / l_acc[mi][r];
            const int n = r0g + mi * 16 + hi * 4 + r;
#pragma unroll
            for (int ni = 0; ni < 4; ++ni) {
                out[((size_t)bb * N_ + n) * C_ + hh * D_ + lo + 16 * ni] = f2b(o_acc[mi][ni][r] * inv);
            }
        }
}

// ---------------- orchestration ----------------
// Workspace layout (overlapped lifetimes; total ~80.5 MB):
//   Region A (24 MB): Wtqkv | Wtproj | Wtfc1 | Wtfc2          [live: whole launch]
//   Region B (32 MB): qkv(24)  [prologue -> attn]   ... then a1(32)  [fc1 -> fc2]
//   Region C ( 8 MB): h1 [prologue -> qkvGEMM] -> oatt [attn -> proj] -> h2 [ln2 -> fc1]
//   Region D (16 MB): x1 [proj -> end]
//   Region E (0.5MB): tab
extern "C" void kernel_launch(void* const* d_in, const int* in_sizes, int n_in,
                              void* d_out, int out_size, void* d_ws, size_t ws_size,
                              hipStream_t stream) {
    (void)in_sizes; (void)n_in; (void)out_size; (void)ws_size;
    const float* x     = (const float*)d_in[0];
    const float* ln1g  = (const float*)d_in[1];
    const float* ln1b  = (const float*)d_in[2];
    const float* Wqkv  = (const float*)d_in[3];
    const float* bqkv  = (const float*)d_in[4];
    const float* Wproj = (const float*)d_in[5];
    const float* bproj = (const float*)d_in[6];
    const float* ln2g  = (const float*)d_in[7];
    const float* ln2b  = (const float*)d_in[8];
    const float* Wfc1  = (const float*)d_in[9];
    const float* bfc1  = (const float*)d_in[10];
    const float* Wfc2  = (const float*)d_in[11];
    const float* bfc2  = (const float*)d_in[12];
    float* out = (float*)d_out;

    char* base = (char*)d_ws;
    const size_t MB = 1024 * 1024;
    // Region A: weights (24 MB)
    u16* Wtqkv  = (u16*)(base);                    // 6 MB
    u16* Wtproj = (u16*)(base + 6 * MB);           // 2 MB
    u16* Wtfc1  = (u16*)(base + 8 * MB);           // 8 MB
    u16* Wtfc2  = (u16*)(base + 16 * MB);          // 8 MB
    // Region B: 32 MB at +24 MB
    u16* qkv    = (u16*)(base + 24 * MB);          // 24 MB  (3,B,H,N,D) bf16
    u16* a1     = (u16*)(base + 24 * MB);          // 32 MB  gelu(fc1), overlays qkv
    // Region C: 8 MB at +56 MB
    u16* h1     = (u16*)(base + 56 * MB);          // LN1 out bf16
    u16* oatt   = (u16*)(base + 56 * MB);          // attn out, overlays h1
    u16* h2     = (u16*)(base + 56 * MB);          // LN2 out, overlays oatt
    // Region D: 16 MB at +64 MB
    float* x1   = (float*)(base + 64 * MB);        // residual after attn, fp32
    // Region E: tab at +80 MB
    float2* tab = (float2*)(base + 80 * MB);       // 0.5 MB

    transpose_all<<<16640, 256, 0, stream>>>(Wqkv, Wproj, Wfc1, Wfc2,
                                             Wtqkv, Wtproj, Wtfc1, Wtfc2, tab,
                                             x, ln1g, ln1b, h1);
    gemm_bt<0, 128><<<dim3(3 * C_ / 128, M_ / 128), 256, 0, stream>>>(h1, Wtqkv, bqkv, qkv, nullptr, tab, 3 * C_, C_);
    attn_mfma<<<dim3(N_ / 128, B_ * H_), 256, 0, stream>>>(
        qkv, qkv + (size_t)B_ * H_ * N_ * D_, qkv + (size_t)2 * B_ * H_ * N_ * D_, oatt);
    gemm_bk64<<<dim3(C_ / 128, M_ / 64), 256, 0, stream>>>(oatt, Wtproj, bproj, x1, x, C_, C_);
    ln_kernel<<<M_, 256, 0, stream>>>(x1, ln2g, ln2b, h2);
    gemm256_gelu<<<dim3(HID_ / 256, M_ / 256), 512, 0, stream>>>(h2, Wtfc1, bfc1, a1, HID_, C_);
    gemm_bk64<<<dim3(C_ / 128, M_ / 64), 256, 0, stream>>>(a1, Wtfc2, bfc2, out, x1, C_, HID_);
}